// Round 4
// baseline (351.775 us; speedup 1.0000x reference)
//
#include <hip/hip_runtime.h>
#include <hip/hip_bf16.h>

#define B_ 16
#define CIN_ 512
#define COUT_ 512
#define SDIM_ 512
#define HIN_ 32
#define WIN_ 32
#define HOUT_ 64
#define WOUT_ 64

#define LIN_SCALE_C 0.044194173824159216f
#define CONV_SCALE_C 0.014731391274719742f

typedef short short8 __attribute__((ext_vector_type(8)));
typedef float f32x4 __attribute__((ext_vector_type(4)));

typedef const __attribute__((address_space(1))) void* gptr_t;
typedef __attribute__((address_space(3))) void* sptr_t;

__device__ __forceinline__ void glds16(const void* g, void* l) {
    __builtin_amdgcn_global_load_lds((gptr_t)g, (sptr_t)l, 16, 0, 0);
}

// ---------------- style: s[b,i] = LIN_SCALE * dot(w[b,:], lin_w[i,:]) + lin_b[i]
__global__ void style_kernel(const float* __restrict__ w, const float* __restrict__ lin_w,
                             const float* __restrict__ lin_b, float* __restrict__ s) {
    const int i = blockIdx.x * 256 + threadIdx.x;   // 0..511
    const int b = blockIdx.y;
    const float* wr = w + b * SDIM_;
    const float* lw = lin_w + i * SDIM_;
    float acc = 0.f;
    #pragma unroll 4
    for (int j = 0; j < SDIM_; ++j) acc += wr[j] * lw[j];
    s[b * CIN_ + i] = acc * LIN_SCALE_C + lin_b[i];
}

// ---------------- weights: w2[o][kk][i] = bf16(conv_w[o][i][kk]*CS); wsq[o][i] = sum_kk wk^2
__global__ void prep_weights(const float* __restrict__ conv_w, __hip_bfloat16* __restrict__ w2,
                             float* __restrict__ wsq, float* __restrict__ zbuf) {
    const int o = blockIdx.x;
    for (int i = threadIdx.x; i < CIN_; i += 256) {
        const float* src = conv_w + (o * CIN_ + i) * 9;
        float ss = 0.f;
        #pragma unroll
        for (int kk = 0; kk < 9; ++kk) {
            float v = src[kk] * CONV_SCALE_C;
            ss += v * v;
            w2[o * 4608 + kk * 512 + i] = __float2bfloat16(v);
        }
        wsq[o * CIN_ + i] = ss;
    }
    if (blockIdx.x == 0 && threadIdx.x < 64) zbuf[threadIdx.x] = 0.f;  // zero page for OOB halo
}

// ---------------- demod[b,o] = 1/sqrt(sum_i wsq[o,i]*s[b,i]^2 + eps)
__global__ void demod_kernel(const float* __restrict__ wsq, const float* __restrict__ s,
                             float* __restrict__ demod) {
    const int o = blockIdx.x * 256 + threadIdx.x;
    const int b = blockIdx.y;
    const float* sr = s + b * CIN_;
    const float* wr = wsq + o * CIN_;
    float acc = 0.f;
    #pragma unroll 4
    for (int i = 0; i < CIN_; ++i) { float sv = sr[i]; acc += wr[i] * sv * sv; }
    demod[b * COUT_ + o] = 1.0f / sqrtf(acc + 1e-8f);
}

// ---------------- bilinear 2x upsample + modulate, NCHW fp32 -> NHWC bf16
__global__ void upsample_mod_kernel(const float* __restrict__ x, const float* __restrict__ s,
                                    __hip_bfloat16* __restrict__ xq) {
    __shared__ float xs[10 * 32 * 33];  // [row 10][col 32][ch 33-padded]
    const int ht = blockIdx.x;          // 0..3  -> 16 output rows
    const int ct = blockIdx.y;          // 0..15 -> 32 channels
    const int b  = blockIdx.z;
    const int tid = threadIdx.x;
    const int ho0 = ht * 16, h0 = ht * 8, c0 = ct * 32;

    for (int idx = tid; idx < 10240; idx += 256) {
        int ch = idx / 320; int rem = idx - ch * 320;
        int rr = rem >> 5;  int col = rem & 31;
        int srow = h0 - 1 + rr; srow = min(max(srow, 0), 31);
        xs[(rr * 32 + col) * 33 + ch] = x[((b * CIN_ + c0 + ch) * HIN_ + srow) * WIN_ + col];
    }
    __syncthreads();

    for (int e = tid; e < 32768; e += 256) {
        int c = e & 31; int rest = e >> 5; int wo = rest & 63; int hr = rest >> 6;
        int ri0 = (hr + (hr & 1)) >> 1;
        float wlo_h = (hr & 1) ? 0.75f : 0.25f;
        int clo = (wo - 2 + (wo & 1)) >> 1;
        float wlo_w = (wo & 1) ? 0.75f : 0.25f;
        int chi = min(clo + 1, 31); clo = max(clo, 0);
        float v0 = xs[(ri0 * 32 + clo) * 33 + c];
        float v1 = xs[(ri0 * 32 + chi) * 33 + c];
        float v2 = xs[((ri0 + 1) * 32 + clo) * 33 + c];
        float v3 = xs[((ri0 + 1) * 32 + chi) * 33 + c];
        float rlo = wlo_w * v0 + (1.f - wlo_w) * v1;
        float rhi = wlo_w * v2 + (1.f - wlo_w) * v3;
        float val = (wlo_h * rlo + (1.f - wlo_h) * rhi) * s[b * CIN_ + c0 + c];
        xq[(((b * HOUT_ + ho0 + hr) * WOUT_) + wo) * CIN_ + c0 + c] = __float2bfloat16(val);
    }
}

#define MFMA_ROW(am, bi0, bi1, bi2, bi3, mi) \
    acc[mi][0] = __builtin_amdgcn_mfma_f32_16x16x32_bf16(am, bi0, acc[mi][0], 0, 0, 0); \
    acc[mi][1] = __builtin_amdgcn_mfma_f32_16x16x32_bf16(am, bi1, acc[mi][1], 0, 0, 0); \
    acc[mi][2] = __builtin_amdgcn_mfma_f32_16x16x32_bf16(am, bi2, acc[mi][2], 0, 0, 0); \
    acc[mi][3] = __builtin_amdgcn_mfma_f32_16x16x32_bf16(am, bi3, acc[mi][3], 0, 0, 0)

// ---------------- implicit-GEMM conv, 256x256 tile, BK=32, 4-deep LDS ring, counted vmcnt,
// chunk-XOR LDS swizzle (both-sides), ds_read/MFMA fine interleave via sched_group_barrier.
__global__ __launch_bounds__(512)
void conv_kernel(const __hip_bfloat16* __restrict__ xq,
                 const __hip_bfloat16* __restrict__ w2,
                 const float* __restrict__ demod,
                 const float* __restrict__ noise,
                 const float* __restrict__ nw_p,
                 float* __restrict__ out,
                 const __hip_bfloat16* __restrict__ zbuf) {
    extern __shared__ __hip_bfloat16 smem[];
    __hip_bfloat16* As = smem;           // 4 slots x [256][32] (64 KB)
    __hip_bfloat16* Bs = smem + 32768;   // 4 slots x [256][32] (64 KB)

    const int bid = blockIdx.x;
    const int swz = (bid & 7) * 64 + (bid >> 3);
    const int b  = swz >> 5;          // 16 batches
    const int mt = (swz >> 4) & 1;    // 2 cout tiles
    const int nt = swz & 15;          // 16 pixel tiles (4 rows x 64 cols each)
    const int o0 = mt * 256;
    const int p0 = nt * 256;

    const int tid  = threadIdx.x;
    const int lane = tid & 63;
    const int wave = tid >> 6;
    const int wm = wave >> 2, wn = wave & 3;   // 2M x 4N waves, each 128x64 out

    // ---- staging coords: 4 threads per row (64B); SOURCE chunk is swizzle-permuted
    const int srow = tid >> 2;            // 0..127
    const int schk = (((tid & 3) ^ ((tid >> 3) & 3))) * 8;   // swizzled source chunk (elements)
    const int aoff = (o0 + srow) * 4608 + schk;              // + h*128*4608 + u*32
    const int brow_lo = nt * 4 + (srow >> 6);                // + h*2 + dh
    const int bcol = srow & 63;
    const int sdst = tid * 8;             // LINEAR dest: + slot*8192 + h*4096 (elements)

    // ---- frag read offsets (elements, within slot), swizzled chunk
    const int lrow = lane & 15;
    const int pko = ((lane >> 4) ^ ((lrow >> 1) & 3)) * 8;   // phys chunk of logical k-chunk
    const int ard = (wm * 128 + lrow) * 32 + pko;            // + m*512
    const int brd = (wn * 64 + lrow) * 32 + pko;             // + n*512

    f32x4 acc[8][4] = {};

    #define STAGE_A(u, h) \
        glds16(w2 + aoff + (h) * 589824 + (u) * 32, As + (((u) & 3) << 13) + ((h) << 12) + sdst)
    #define STAGE_B(u, h, dh, dw, i0) do { \
        int rr_ = brow_lo + (h) * 2 + (dh); \
        int cc_ = bcol + (dw); \
        bool v_ = ((unsigned)rr_ < 64u) && ((unsigned)cc_ < 64u); \
        const __hip_bfloat16* src_ = v_ ? xq + ((b * 64 + rr_) * 64 + cc_) * 512 + (i0) + schk : zbuf; \
        glds16(src_, Bs + (((u) & 3) << 13) + ((h) << 12) + sdst); \
    } while (0)

    // prologue: stage tiles 0 and 1 (both in kk=0: dh=dw=-1)
    STAGE_A(0, 0); STAGE_A(0, 1); STAGE_B(0, 0, -1, -1, 0);  STAGE_B(0, 1, -1, -1, 0);
    STAGE_A(1, 0); STAGE_A(1, 1); STAGE_B(1, 0, -1, -1, 32); STAGE_B(1, 1, -1, -1, 32);
    asm volatile("s_waitcnt vmcnt(4)" ::: "memory");   // tile 0 fully landed
    __builtin_amdgcn_s_barrier();

    #pragma unroll 4
    for (int t = 0; t < 144; ++t) {
        const int slot = (t & 3) << 13;
        const __hip_bfloat16* As_s = As + slot + ard;
        const __hip_bfloat16* Bs_s = Bs + slot + brd;

        // issue next-next tile staging first (in flight for the whole window)
        const int u = t + 2;
        if (u < 144) {
            const int kk = u >> 4;
            const int i0 = (u & 15) << 5;
            const int kd = (kk * 11) >> 5;       // kk/3
            const int dh = kd - 1, dw = kk - kd * 3 - 1;
            STAGE_A(u, 0); STAGE_A(u, 1);
            STAGE_B(u, 0, dh, dw, i0); STAGE_B(u, 1, dh, dw, i0);
        }

        short8 bf0 = *(const short8*)(Bs_s + 0 * 512);
        short8 bf1 = *(const short8*)(Bs_s + 1 * 512);
        short8 bf2 = *(const short8*)(Bs_s + 2 * 512);
        short8 bf3 = *(const short8*)(Bs_s + 3 * 512);
        short8 a0  = *(const short8*)(As_s + 0 * 512);
        short8 a1  = *(const short8*)(As_s + 1 * 512);

        __builtin_amdgcn_s_setprio(1);
        MFMA_ROW(a0, bf0, bf1, bf2, bf3, 0);
        short8 a2 = *(const short8*)(As_s + 2 * 512);
        short8 a3 = *(const short8*)(As_s + 3 * 512);
        MFMA_ROW(a1, bf0, bf1, bf2, bf3, 1);
        short8 a4 = *(const short8*)(As_s + 4 * 512);
        short8 a5 = *(const short8*)(As_s + 5 * 512);
        MFMA_ROW(a2, bf0, bf1, bf2, bf3, 2);
        short8 a6 = *(const short8*)(As_s + 6 * 512);
        short8 a7 = *(const short8*)(As_s + 7 * 512);
        MFMA_ROW(a3, bf0, bf1, bf2, bf3, 3);
        MFMA_ROW(a4, bf0, bf1, bf2, bf3, 4);
        MFMA_ROW(a5, bf0, bf1, bf2, bf3, 5);
        MFMA_ROW(a6, bf0, bf1, bf2, bf3, 6);
        MFMA_ROW(a7, bf0, bf1, bf2, bf3, 7);
        __builtin_amdgcn_s_setprio(0);

        // emission template: interleave {4 MFMA | 2 ds_read} so the LDS pipe is fed
        // while the matrix pipe executes (masks per m137: MFMA=0x8, DS_READ=0x100)
        __builtin_amdgcn_sched_group_barrier(0x100, 6, 0);  // bf0-3, a0, a1
        __builtin_amdgcn_sched_group_barrier(0x008, 4, 0);  // a0 row
        __builtin_amdgcn_sched_group_barrier(0x100, 2, 0);  // a2, a3
        __builtin_amdgcn_sched_group_barrier(0x008, 4, 0);  // a1 row
        __builtin_amdgcn_sched_group_barrier(0x100, 2, 0);  // a4, a5
        __builtin_amdgcn_sched_group_barrier(0x008, 4, 0);  // a2 row
        __builtin_amdgcn_sched_group_barrier(0x100, 2, 0);  // a6, a7
        __builtin_amdgcn_sched_group_barrier(0x008, 20, 0); // remaining rows

        // counted wait: tile t+1 (staged last window) complete; this window's 4 in flight
        if (t < 142) asm volatile("s_waitcnt vmcnt(4)" ::: "memory");
        else         asm volatile("s_waitcnt vmcnt(0)" ::: "memory");
        __builtin_amdgcn_s_barrier();
    }
    #undef STAGE_A
    #undef STAGE_B

    // epilogue: demod * acc + nw*noise, leaky-relu * sqrt(2)
    const float nwv = nw_p[0];
    const int colp = lane & 15;
    const int rgrp = (lane >> 4) * 4;
    float nz[4];
    #pragma unroll
    for (int ni = 0; ni < 4; ++ni)
        nz[ni] = noise[b * 4096 + p0 + wn * 64 + ni * 16 + colp] * nwv;
    #pragma unroll
    for (int mi = 0; mi < 8; ++mi) {
        const int obase = o0 + wm * 128 + mi * 16 + rgrp;
        float dm[4];
        #pragma unroll
        for (int j = 0; j < 4; ++j) dm[j] = demod[b * COUT_ + obase + j];
        #pragma unroll
        for (int ni = 0; ni < 4; ++ni) {
            const int pix = p0 + wn * 64 + ni * 16 + colp;
            #pragma unroll
            for (int j = 0; j < 4; ++j) {
                float v = acc[mi][ni][j] * dm[j] + nz[ni];
                v = (v >= 0.f ? v : 0.2f * v) * 1.4142135623730951f;
                out[(b * COUT_ + obase + j) * 4096 + pix] = v;
            }
        }
    }
}

extern "C" void kernel_launch(void* const* d_in, const int* in_sizes, int n_in,
                              void* d_out, int out_size, void* d_ws, size_t ws_size,
                              hipStream_t stream) {
    const float* x      = (const float*)d_in[0];
    const float* w      = (const float*)d_in[1];
    const float* noise  = (const float*)d_in[2];
    const float* lin_w  = (const float*)d_in[3];
    const float* lin_b  = (const float*)d_in[4];
    const float* conv_w = (const float*)d_in[5];
    const float* nw     = (const float*)d_in[6];
    float* out = (float*)d_out;

    char* ws = (char*)d_ws;
    __hip_bfloat16* xq = (__hip_bfloat16*)ws;                    // 67108864 B (NHWC bf16)
    __hip_bfloat16* w2 = (__hip_bfloat16*)(ws + 67108864);       //  4718592 B
    float* s     = (float*)(ws + 71827456);                      //    32768 B
    float* demod = (float*)(ws + 71860224);                      //    32768 B
    float* wsq   = (float*)(ws + 71892992);                      //  1048576 B
    float* zbuf  = (float*)(ws + 72941568);                      //      256 B (zero page)

    static int lds_set = 0;
    if (!lds_set) {
        (void)hipFuncSetAttribute((const void*)conv_kernel,
                                  hipFuncAttributeMaxDynamicSharedMemorySize, 131072);
        lds_set = 1;
    }

    style_kernel<<<dim3(2, 16), 256, 0, stream>>>(w, lin_w, lin_b, s);
    prep_weights<<<512, 256, 0, stream>>>(conv_w, w2, wsq, zbuf);
    demod_kernel<<<dim3(2, 16), 256, 0, stream>>>(wsq, s, demod);
    upsample_mod_kernel<<<dim3(4, 16, 16), 256, 0, stream>>>(x, s, xq);
    conv_kernel<<<512, 512, 131072, stream>>>(xq, w2, demod, noise, nw, out,
                                              (const __hip_bfloat16*)zbuf);
}

// Round 5
// 320.534 us; speedup vs baseline: 1.0975x; 1.0975x over previous
//
#include <hip/hip_runtime.h>
#include <hip/hip_bf16.h>

#define B_ 16
#define CIN_ 512
#define COUT_ 512
#define SDIM_ 512
#define HIN_ 32
#define WIN_ 32
#define HOUT_ 64
#define WOUT_ 64

#define LIN_SCALE_C 0.044194173824159216f
#define CONV_SCALE_C 0.014731391274719742f

typedef short short8 __attribute__((ext_vector_type(8)));
typedef float f32x4 __attribute__((ext_vector_type(4)));

typedef const __attribute__((address_space(1))) void* gptr_t;
typedef __attribute__((address_space(3))) void* sptr_t;

__device__ __forceinline__ void glds16(const void* g, void* l) {
    __builtin_amdgcn_global_load_lds((gptr_t)g, (sptr_t)l, 16, 0, 0);
}

// ---------------- style: one wave per (b,i); shuffle-reduce 512-dot
__global__ void style_kernel(const float* __restrict__ w, const float* __restrict__ lin_w,
                             const float* __restrict__ lin_b, float* __restrict__ s) {
    const int gw   = (blockIdx.x * 256 + threadIdx.x) >> 6;   // 0..8191
    const int lane = threadIdx.x & 63;
    const int b = gw >> 9, i = gw & 511;
    const float* wr = w + b * SDIM_;
    const float* lw = lin_w + i * SDIM_;
    float acc = 0.f;
    #pragma unroll
    for (int j = 0; j < 8; ++j) acc += wr[lane + j * 64] * lw[lane + j * 64];
    #pragma unroll
    for (int off = 32; off; off >>= 1) acc += __shfl_xor(acc, off);
    if (lane == 0) s[b * CIN_ + i] = acc * LIN_SCALE_C + lin_b[i];
}

// ---------------- weights: w2[o][kk][i] = bf16(conv_w[o][i][kk]*CS); wsq[o][i] = sum_kk wk^2
__global__ void prep_weights(const float* __restrict__ conv_w, __hip_bfloat16* __restrict__ w2,
                             float* __restrict__ wsq, float* __restrict__ zbuf) {
    const int o = blockIdx.x;
    for (int i = threadIdx.x; i < CIN_; i += 256) {
        const float* src = conv_w + (o * CIN_ + i) * 9;
        float ss = 0.f;
        #pragma unroll
        for (int kk = 0; kk < 9; ++kk) {
            float v = src[kk] * CONV_SCALE_C;
            ss += v * v;
            w2[o * 4608 + kk * 512 + i] = __float2bfloat16(v);
        }
        wsq[o * CIN_ + i] = ss;
    }
    if (blockIdx.x == 0 && threadIdx.x < 64) zbuf[threadIdx.x] = 0.f;  // zero page for OOB halo
}

// ---------------- demod: one wave per (b,o); shuffle-reduce
__global__ void demod_kernel(const float* __restrict__ wsq, const float* __restrict__ s,
                             float* __restrict__ demod) {
    const int gw   = (blockIdx.x * 256 + threadIdx.x) >> 6;
    const int lane = threadIdx.x & 63;
    const int b = gw >> 9, o = gw & 511;
    const float* sr = s + b * CIN_;
    const float* wr = wsq + o * CIN_;
    float acc = 0.f;
    #pragma unroll
    for (int j = 0; j < 8; ++j) {
        float sv = sr[lane + j * 64];
        acc += wr[lane + j * 64] * sv * sv;
    }
    #pragma unroll
    for (int off = 32; off; off >>= 1) acc += __shfl_xor(acc, off);
    if (lane == 0) demod[b * COUT_ + o] = 1.0f / sqrtf(acc + 1e-8f);
}

// ---------------- bilinear 2x upsample + modulate, NCHW fp32 -> NHWC bf16
__global__ void upsample_mod_kernel(const float* __restrict__ x, const float* __restrict__ s,
                                    __hip_bfloat16* __restrict__ xq) {
    __shared__ float xs[10 * 32 * 33];  // [row 10][col 32][ch 33-padded]
    const int ht = blockIdx.x;          // 0..3  -> 16 output rows
    const int ct = blockIdx.y;          // 0..15 -> 32 channels
    const int b  = blockIdx.z;
    const int tid = threadIdx.x;
    const int ho0 = ht * 16, h0 = ht * 8, c0 = ct * 32;

    for (int idx = tid; idx < 10240; idx += 256) {
        int ch = idx / 320; int rem = idx - ch * 320;
        int rr = rem >> 5;  int col = rem & 31;
        int srow = h0 - 1 + rr; srow = min(max(srow, 0), 31);
        xs[(rr * 32 + col) * 33 + ch] = x[((b * CIN_ + c0 + ch) * HIN_ + srow) * WIN_ + col];
    }
    __syncthreads();

    for (int e = tid; e < 32768; e += 256) {
        int c = e & 31; int rest = e >> 5; int wo = rest & 63; int hr = rest >> 6;
        int ri0 = (hr + (hr & 1)) >> 1;
        float wlo_h = (hr & 1) ? 0.75f : 0.25f;
        int clo = (wo - 2 + (wo & 1)) >> 1;
        float wlo_w = (wo & 1) ? 0.75f : 0.25f;
        int chi = min(clo + 1, 31); clo = max(clo, 0);
        float v0 = xs[(ri0 * 32 + clo) * 33 + c];
        float v1 = xs[(ri0 * 32 + chi) * 33 + c];
        float v2 = xs[((ri0 + 1) * 32 + clo) * 33 + c];
        float v3 = xs[((ri0 + 1) * 32 + chi) * 33 + c];
        float rlo = wlo_w * v0 + (1.f - wlo_w) * v1;
        float rhi = wlo_w * v2 + (1.f - wlo_w) * v3;
        float val = (wlo_h * rlo + (1.f - wlo_h) * rhi) * s[b * CIN_ + c0 + c];
        xq[(((b * HOUT_ + ho0 + hr) * WOUT_) + wo) * CIN_ + c0 + c] = __float2bfloat16(val);
    }
}

// ---------------- implicit-GEMM conv, 256x256 tile, BK=32, 4-deep LDS ring, counted vmcnt,
// chunk-XOR LDS swizzle (both-sides), cross-window REGISTER double-buffer:
// window t MFMAs tile-t frags (read during window t-1) while ds_reads for tile t+1
// drain in the LDS pipe underneath the MFMA block.
__global__ __launch_bounds__(512)
void conv_kernel(const __hip_bfloat16* __restrict__ xq,
                 const __hip_bfloat16* __restrict__ w2,
                 const float* __restrict__ demod,
                 const float* __restrict__ noise,
                 const float* __restrict__ nw_p,
                 float* __restrict__ out,
                 const __hip_bfloat16* __restrict__ zbuf) {
    extern __shared__ __hip_bfloat16 smem[];
    __hip_bfloat16* As = smem;           // 4 slots x [256][32] (64 KB)
    __hip_bfloat16* Bs = smem + 32768;   // 4 slots x [256][32] (64 KB)

    const int bid = blockIdx.x;
    const int swz = (bid & 7) * 64 + (bid >> 3);
    const int b  = swz >> 5;          // 16 batches
    const int mt = (swz >> 4) & 1;    // 2 cout tiles
    const int nt = swz & 15;          // 16 pixel tiles (4 rows x 64 cols each)
    const int o0 = mt * 256;
    const int p0 = nt * 256;

    const int tid  = threadIdx.x;
    const int lane = tid & 63;
    const int wave = tid >> 6;
    const int wm = wave >> 2, wn = wave & 3;   // 2M x 4N waves, each 128x64 out

    // ---- staging coords: 4 threads per row (64B); SOURCE chunk is swizzle-permuted
    const int srow = tid >> 2;            // 0..127
    const int schk = (((tid & 3) ^ ((tid >> 3) & 3))) * 8;   // swizzled source chunk (elements)
    const int aoff = (o0 + srow) * 4608 + schk;              // + h*128*4608 + u*32
    const int brow_lo = nt * 4 + (srow >> 6);                // + h*2 + dh
    const int bcol = srow & 63;
    const int sdst = tid * 8;             // LINEAR dest: + slot*8192 + h*4096 (elements)

    // ---- frag read offsets (elements, within slot), swizzled chunk
    const int lrow = lane & 15;
    const int pko = ((lane >> 4) ^ ((lrow >> 1) & 3)) * 8;   // phys chunk of logical k-chunk
    const int ard = (wm * 128 + lrow) * 32 + pko;            // + m*512
    const int brd = (wn * 64 + lrow) * 32 + pko;             // + n*512

    f32x4 acc[8][4] = {};
    short8 fa[12], fb[12];   // [0..3] = B frags, [4..11] = A frags; static indices only

    #define STAGE_A(u, h) \
        glds16(w2 + aoff + (h) * 589824 + (u) * 32, As + (((u) & 3) << 13) + ((h) << 12) + sdst)
    #define STAGE_B(u, h, dh, dw, i0) do { \
        int rr_ = brow_lo + (h) * 2 + (dh); \
        int cc_ = bcol + (dw); \
        bool v_ = ((unsigned)rr_ < 64u) && ((unsigned)cc_ < 64u); \
        const __hip_bfloat16* src_ = v_ ? xq + ((b * 64 + rr_) * 64 + cc_) * 512 + (i0) + schk : zbuf; \
        glds16(src_, Bs + (((u) & 3) << 13) + ((h) << 12) + sdst); \
    } while (0)
    #define STAGE_TILE(u) do { \
        const int kk_ = (u) >> 4; \
        const int i0_ = ((u) & 15) << 5; \
        const int kd_ = (kk_ * 11) >> 5; \
        const int dh_ = kd_ - 1, dw_ = kk_ - kd_ * 3 - 1; \
        STAGE_A(u, 0); STAGE_A(u, 1); \
        STAGE_B(u, 0, dh_, dw_, i0_); STAGE_B(u, 1, dh_, dw_, i0_); \
    } while (0)
    #define READS(T1, NXT) do { \
        const int slot_ = ((T1) & 3) << 13; \
        const __hip_bfloat16* Ap_ = As + slot_ + ard; \
        const __hip_bfloat16* Bp_ = Bs + slot_ + brd; \
        NXT[0]  = *(const short8*)(Bp_ + 0 * 512); \
        NXT[1]  = *(const short8*)(Bp_ + 1 * 512); \
        NXT[2]  = *(const short8*)(Bp_ + 2 * 512); \
        NXT[3]  = *(const short8*)(Bp_ + 3 * 512); \
        NXT[4]  = *(const short8*)(Ap_ + 0 * 512); \
        NXT[5]  = *(const short8*)(Ap_ + 1 * 512); \
        NXT[6]  = *(const short8*)(Ap_ + 2 * 512); \
        NXT[7]  = *(const short8*)(Ap_ + 3 * 512); \
        NXT[8]  = *(const short8*)(Ap_ + 4 * 512); \
        NXT[9]  = *(const short8*)(Ap_ + 5 * 512); \
        NXT[10] = *(const short8*)(Ap_ + 6 * 512); \
        NXT[11] = *(const short8*)(Ap_ + 7 * 512); \
    } while (0)
    #define MFMAS(CUR) do { \
        __builtin_amdgcn_s_setprio(1); \
        _Pragma("unroll") \
        for (int m_ = 0; m_ < 8; ++m_) \
            _Pragma("unroll") \
            for (int n_ = 0; n_ < 4; ++n_) \
                acc[m_][n_] = __builtin_amdgcn_mfma_f32_16x16x32_bf16(CUR[4 + m_], CUR[n_], acc[m_][n_], 0, 0, 0); \
        __builtin_amdgcn_s_setprio(0); \
    } while (0)
    // emission template: all 12 prefetch ds_reads BEFORE the 32-MFMA cluster, so the
    // LDS pipe drains them while the matrix pipe executes (no consumer this window)
    #define BODY(W, CUR, NXT) do { \
        STAGE_TILE((W) + 2); \
        asm volatile("s_waitcnt vmcnt(4)" ::: "memory"); \
        __builtin_amdgcn_s_barrier(); \
        READS((W) + 1, NXT); \
        MFMAS(CUR); \
        __builtin_amdgcn_sched_group_barrier(0x100, 12, 0); \
        __builtin_amdgcn_sched_group_barrier(0x008, 32, 0); \
    } while (0)

    // prologue: stage tiles 0,1; read tile-0 frags
    STAGE_TILE(0); STAGE_TILE(1);
    asm volatile("s_waitcnt vmcnt(4)" ::: "memory");   // tile 0 landed
    __builtin_amdgcn_s_barrier();
    READS(0, fa);

    #pragma unroll 1
    for (int t = 0; t < 142; t += 2) {
        BODY(t, fa, fb);
        BODY(t + 1, fb, fa);
    }
    // window 142: no stage left; drain tile 143
    asm volatile("s_waitcnt vmcnt(0)" ::: "memory");
    __builtin_amdgcn_s_barrier();
    READS(143, fb);
    MFMAS(fa);
    // window 143
    MFMAS(fb);

    #undef STAGE_A
    #undef STAGE_B
    #undef STAGE_TILE
    #undef READS
    #undef MFMAS
    #undef BODY

    // epilogue: demod * acc + nw*noise, leaky-relu * sqrt(2)
    const float nwv = nw_p[0];
    const int colp = lane & 15;
    const int rgrp = (lane >> 4) * 4;
    float nz[4];
    #pragma unroll
    for (int ni = 0; ni < 4; ++ni)
        nz[ni] = noise[b * 4096 + p0 + wn * 64 + ni * 16 + colp] * nwv;
    #pragma unroll
    for (int mi = 0; mi < 8; ++mi) {
        const int obase = o0 + wm * 128 + mi * 16 + rgrp;
        float dm[4];
        #pragma unroll
        for (int j = 0; j < 4; ++j) dm[j] = demod[b * COUT_ + obase + j];
        #pragma unroll
        for (int ni = 0; ni < 4; ++ni) {
            const int pix = p0 + wn * 64 + ni * 16 + colp;
            #pragma unroll
            for (int j = 0; j < 4; ++j) {
                float v = acc[mi][ni][j] * dm[j] + nz[ni];
                v = (v >= 0.f ? v : 0.2f * v) * 1.4142135623730951f;
                out[(b * COUT_ + obase + j) * 4096 + pix] = v;
            }
        }
    }
}

extern "C" void kernel_launch(void* const* d_in, const int* in_sizes, int n_in,
                              void* d_out, int out_size, void* d_ws, size_t ws_size,
                              hipStream_t stream) {
    const float* x      = (const float*)d_in[0];
    const float* w      = (const float*)d_in[1];
    const float* noise  = (const float*)d_in[2];
    const float* lin_w  = (const float*)d_in[3];
    const float* lin_b  = (const float*)d_in[4];
    const float* conv_w = (const float*)d_in[5];
    const float* nw     = (const float*)d_in[6];
    float* out = (float*)d_out;

    char* ws = (char*)d_ws;
    __hip_bfloat16* xq = (__hip_bfloat16*)ws;                    // 67108864 B (NHWC bf16)
    __hip_bfloat16* w2 = (__hip_bfloat16*)(ws + 67108864);       //  4718592 B
    float* s     = (float*)(ws + 71827456);                      //    32768 B
    float* demod = (float*)(ws + 71860224);                      //    32768 B
    float* wsq   = (float*)(ws + 71892992);                      //  1048576 B
    float* zbuf  = (float*)(ws + 72941568);                      //      256 B (zero page)

    static int lds_set = 0;
    if (!lds_set) {
        (void)hipFuncSetAttribute((const void*)conv_kernel,
                                  hipFuncAttributeMaxDynamicSharedMemorySize, 131072);
        lds_set = 1;
    }

    style_kernel<<<2048, 256, 0, stream>>>(w, lin_w, lin_b, s);
    prep_weights<<<512, 256, 0, stream>>>(conv_w, w2, wsq, zbuf);
    demod_kernel<<<2048, 256, 0, stream>>>(wsq, s, demod);
    upsample_mod_kernel<<<dim3(4, 16, 16), 256, 0, stream>>>(x, s, xq);
    conv_kernel<<<512, 512, 131072, stream>>>(xq, w2, demod, noise, nw, out,
                                              (const __hip_bfloat16*)zbuf);
}

// Round 7
// 320.025 us; speedup vs baseline: 1.0992x; 1.0016x over previous
//
#include <hip/hip_runtime.h>
#include <hip/hip_bf16.h>

#define B_ 16
#define CIN_ 512
#define COUT_ 512
#define SDIM_ 512
#define HIN_ 32
#define WIN_ 32
#define HOUT_ 64
#define WOUT_ 64

#define LIN_SCALE_C 0.044194173824159216f
#define CONV_SCALE_C 0.014731391274719742f

typedef short short8 __attribute__((ext_vector_type(8)));
typedef float f32x4 __attribute__((ext_vector_type(4)));

typedef const __attribute__((address_space(1))) void* gptr_t;
typedef __attribute__((address_space(3))) void* sptr_t;

__device__ __forceinline__ void glds16(const void* g, void* l) {
    __builtin_amdgcn_global_load_lds((gptr_t)g, (sptr_t)l, 16, 0, 0);
}

// ---------------- style: one wave per (b,i); shuffle-reduce 512-dot
__global__ void style_kernel(const float* __restrict__ w, const float* __restrict__ lin_w,
                             const float* __restrict__ lin_b, float* __restrict__ s) {
    const int gw   = (blockIdx.x * 256 + threadIdx.x) >> 6;   // 0..8191
    const int lane = threadIdx.x & 63;
    const int b = gw >> 9, i = gw & 511;
    const float* wr = w + b * SDIM_;
    const float* lw = lin_w + i * SDIM_;
    float acc = 0.f;
    #pragma unroll
    for (int j = 0; j < 8; ++j) acc += wr[lane + j * 64] * lw[lane + j * 64];
    #pragma unroll
    for (int off = 32; off; off >>= 1) acc += __shfl_xor(acc, off);
    if (lane == 0) s[b * CIN_ + i] = acc * LIN_SCALE_C + lin_b[i];
}

// ---------------- weights: w2[o][kk][i] = bf16(conv_w[o][i][kk]*CS); wsq[o][i] = sum_kk wk^2
__global__ void prep_weights(const float* __restrict__ conv_w, __hip_bfloat16* __restrict__ w2,
                             float* __restrict__ wsq, float* __restrict__ zbuf) {
    const int o = blockIdx.x;
    for (int i = threadIdx.x; i < CIN_; i += 256) {
        const float* src = conv_w + (o * CIN_ + i) * 9;
        float ss = 0.f;
        #pragma unroll
        for (int kk = 0; kk < 9; ++kk) {
            float v = src[kk] * CONV_SCALE_C;
            ss += v * v;
            w2[o * 4608 + kk * 512 + i] = __float2bfloat16(v);
        }
        wsq[o * CIN_ + i] = ss;
    }
    if (blockIdx.x == 0 && threadIdx.x < 64) zbuf[threadIdx.x] = 0.f;  // zero page for OOB halo
}

// ---------------- demod: one wave per (b,o); shuffle-reduce
__global__ void demod_kernel(const float* __restrict__ wsq, const float* __restrict__ s,
                             float* __restrict__ demod) {
    const int gw   = (blockIdx.x * 256 + threadIdx.x) >> 6;
    const int lane = threadIdx.x & 63;
    const int b = gw >> 9, o = gw & 511;
    const float* sr = s + b * CIN_;
    const float* wr = wsq + o * CIN_;
    float acc = 0.f;
    #pragma unroll
    for (int j = 0; j < 8; ++j) {
        float sv = sr[lane + j * 64];
        acc += wr[lane + j * 64] * sv * sv;
    }
    #pragma unroll
    for (int off = 32; off; off >>= 1) acc += __shfl_xor(acc, off);
    if (lane == 0) demod[b * COUT_ + o] = 1.0f / sqrtf(acc + 1e-8f);
}

// ---------------- bilinear 2x upsample + modulate, NCHW fp32 -> NHWC bf16
__global__ void upsample_mod_kernel(const float* __restrict__ x, const float* __restrict__ s,
                                    __hip_bfloat16* __restrict__ xq) {
    __shared__ float xs[10 * 32 * 33];  // [row 10][col 32][ch 33-padded]
    const int ht = blockIdx.x;          // 0..3  -> 16 output rows
    const int ct = blockIdx.y;          // 0..15 -> 32 channels
    const int b  = blockIdx.z;
    const int tid = threadIdx.x;
    const int ho0 = ht * 16, h0 = ht * 8, c0 = ct * 32;

    for (int idx = tid; idx < 10240; idx += 256) {
        int ch = idx / 320; int rem = idx - ch * 320;
        int rr = rem >> 5;  int col = rem & 31;
        int srow = h0 - 1 + rr; srow = min(max(srow, 0), 31);
        xs[(rr * 32 + col) * 33 + ch] = x[((b * CIN_ + c0 + ch) * HIN_ + srow) * WIN_ + col];
    }
    __syncthreads();

    for (int e = tid; e < 32768; e += 256) {
        int c = e & 31; int rest = e >> 5; int wo = rest & 63; int hr = rest >> 6;
        int ri0 = (hr + (hr & 1)) >> 1;
        float wlo_h = (hr & 1) ? 0.75f : 0.25f;
        int clo = (wo - 2 + (wo & 1)) >> 1;
        float wlo_w = (wo & 1) ? 0.75f : 0.25f;
        int chi = min(clo + 1, 31); clo = max(clo, 0);
        float v0 = xs[(ri0 * 32 + clo) * 33 + c];
        float v1 = xs[(ri0 * 32 + chi) * 33 + c];
        float v2 = xs[((ri0 + 1) * 32 + clo) * 33 + c];
        float v3 = xs[((ri0 + 1) * 32 + chi) * 33 + c];
        float rlo = wlo_w * v0 + (1.f - wlo_w) * v1;
        float rhi = wlo_w * v2 + (1.f - wlo_w) * v3;
        float val = (wlo_h * rlo + (1.f - wlo_h) * rhi) * s[b * CIN_ + c0 + c];
        xq[(((b * HOUT_ + ho0 + hr) * WOUT_) + wo) * CIN_ + c0 + c] = __float2bfloat16(val);
    }
}

// ---------------- implicit-GEMM conv, 256x256 tile, BK=32, 2-slot LDS double-buffer
// (64 KB -> 2 blocks/CU; cross-block overlap of LDS-read and MFMA phases).
// Schedule per window t (catalog "minimum 2-phase", verified): STAGE(t+1) ->
// READS(slot t&1) -> MFMA -> vmcnt(0) [waits loads issued a full window ago] -> barrier.
// Chunk-XOR LDS swizzle (both-sides: pre-swizzled global source + swizzled frag read;
// glds16 dest linear). Safety: slot (t+1)&1 was last read in window t-1, and every
// wave's reads complete (lgkmcnt before MFMA) before it reaches the barrier that
// window-t stagers must pass first.
__global__ __launch_bounds__(512)
void conv_kernel(const __hip_bfloat16* __restrict__ xq,
                 const __hip_bfloat16* __restrict__ w2,
                 const float* __restrict__ demod,
                 const float* __restrict__ noise,
                 const float* __restrict__ nw_p,
                 float* __restrict__ out,
                 const __hip_bfloat16* __restrict__ zbuf) {
    extern __shared__ __hip_bfloat16 smem[];
    __hip_bfloat16* As = smem;           // 2 slots x [256][32] = 2 x 8192 elems (32 KB)
    __hip_bfloat16* Bs = smem + 16384;   // 2 slots x [256][32]                  (32 KB)

    const int bid = blockIdx.x;
    const int swz = (bid & 7) * 64 + (bid >> 3);   // 512 blocks, bijective XCD swizzle
    const int b  = swz >> 5;          // 16 batches
    const int mt = (swz >> 4) & 1;    // 2 cout tiles
    const int nt = swz & 15;          // 16 pixel tiles (4 rows x 64 cols each)
    const int o0 = mt * 256;
    const int p0 = nt * 256;

    const int tid  = threadIdx.x;
    const int lane = tid & 63;
    const int wave = tid >> 6;
    const int wm = wave >> 2, wn = wave & 3;   // 2M x 4N waves, each 128x64 out

    // ---- staging coords: 4 threads per row (64B); SOURCE chunk is swizzle-permuted
    const int srow = tid >> 2;            // 0..127
    const int schk = (((tid & 3) ^ ((tid >> 3) & 3))) * 8;   // swizzled source chunk (elements)
    const int aoff = (o0 + srow) * 4608 + schk;              // + h*128*4608 + u*32
    const int brow_lo = nt * 4 + (srow >> 6);                // + h*2 + dh
    const int bcol = srow & 63;
    const int sdst = tid * 8;             // LINEAR dest: + slot*8192 + h*4096 (elements)

    // ---- frag read offsets (elements, within slot), swizzled chunk
    const int lrow = lane & 15;
    const int pko = ((lane >> 4) ^ ((lrow >> 1) & 3)) * 8;   // phys chunk of logical k-chunk
    const int ard = (wm * 128 + lrow) * 32 + pko;            // + m*512
    const int brd = (wn * 64 + lrow) * 32 + pko;             // + n*512

    f32x4 acc[8][4] = {};

    #define STAGE_A(u, h) \
        glds16(w2 + aoff + (h) * 589824 + (u) * 32, As + (((u) & 1) << 13) + ((h) << 12) + sdst)
    #define STAGE_B(u, h, dh, dw, i0) do { \
        int rr_ = brow_lo + (h) * 2 + (dh); \
        int cc_ = bcol + (dw); \
        bool v_ = ((unsigned)rr_ < 64u) && ((unsigned)cc_ < 64u); \
        const __hip_bfloat16* src_ = v_ ? xq + ((b * 64 + rr_) * 64 + cc_) * 512 + (i0) + schk : zbuf; \
        glds16(src_, Bs + (((u) & 1) << 13) + ((h) << 12) + sdst); \
    } while (0)

    // prologue: stage tile 0 (kk=0: dh=dw=-1) into slot 0
    STAGE_A(0, 0); STAGE_A(0, 1); STAGE_B(0, 0, -1, -1, 0); STAGE_B(0, 1, -1, -1, 0);
    asm volatile("s_waitcnt vmcnt(0)" ::: "memory");
    __builtin_amdgcn_s_barrier();

    #pragma unroll 4
    for (int t = 0; t < 144; ++t) {
        // stage next tile into the other slot (read there last window; all waves
        // passed the prior barrier after completing those reads)
        const int u = t + 1;
        if (u < 144) {
            const int kk = u >> 4;
            const int i0 = (u & 15) << 5;
            const int kd = (kk * 11) >> 5;       // kk/3
            const int dh = kd - 1, dw = kk - kd * 3 - 1;
            STAGE_A(u, 0); STAGE_A(u, 1);
            STAGE_B(u, 0, dh, dw, i0); STAGE_B(u, 1, dh, dw, i0);
        }

        const int slot = (t & 1) << 13;
        short8 a[8], bf[4];
        #pragma unroll
        for (int m = 0; m < 8; ++m)
            a[m] = *(const short8*)(As + slot + ard + m * 512);
        #pragma unroll
        for (int n = 0; n < 4; ++n)
            bf[n] = *(const short8*)(Bs + slot + brd + n * 512);

        __builtin_amdgcn_s_setprio(1);
        #pragma unroll
        for (int m = 0; m < 8; ++m)
            #pragma unroll
            for (int n = 0; n < 4; ++n)
                acc[m][n] = __builtin_amdgcn_mfma_f32_16x16x32_bf16(a[m], bf[n], acc[m][n], 0, 0, 0);
        __builtin_amdgcn_s_setprio(0);

        // drain this window's stages (issued ~a full window of reads+MFMA ago -> cheap)
        asm volatile("s_waitcnt vmcnt(0)" ::: "memory");
        __builtin_amdgcn_s_barrier();
    }
    #undef STAGE_A
    #undef STAGE_B

    // epilogue: demod * acc + nw*noise, leaky-relu * sqrt(2)
    const float nwv = nw_p[0];
    const int colp = lane & 15;
    const int rgrp = (lane >> 4) * 4;
    float nz[4];
    #pragma unroll
    for (int ni = 0; ni < 4; ++ni)
        nz[ni] = noise[b * 4096 + p0 + wn * 64 + ni * 16 + colp] * nwv;
    #pragma unroll
    for (int mi = 0; mi < 8; ++mi) {
        const int obase = o0 + wm * 128 + mi * 16 + rgrp;
        float dm[4];
        #pragma unroll
        for (int j = 0; j < 4; ++j) dm[j] = demod[b * COUT_ + obase + j];
        #pragma unroll
        for (int ni = 0; ni < 4; ++ni) {
            const int pix = p0 + wn * 64 + ni * 16 + colp;
            #pragma unroll
            for (int j = 0; j < 4; ++j) {
                float v = acc[mi][ni][j] * dm[j] + nz[ni];
                v = (v >= 0.f ? v : 0.2f * v) * 1.4142135623730951f;
                out[(b * COUT_ + obase + j) * 4096 + pix] = v;
            }
        }
    }
}

extern "C" void kernel_launch(void* const* d_in, const int* in_sizes, int n_in,
                              void* d_out, int out_size, void* d_ws, size_t ws_size,
                              hipStream_t stream) {
    const float* x      = (const float*)d_in[0];
    const float* w      = (const float*)d_in[1];
    const float* noise  = (const float*)d_in[2];
    const float* lin_w  = (const float*)d_in[3];
    const float* lin_b  = (const float*)d_in[4];
    const float* conv_w = (const float*)d_in[5];
    const float* nw     = (const float*)d_in[6];
    float* out = (float*)d_out;

    char* ws = (char*)d_ws;
    __hip_bfloat16* xq = (__hip_bfloat16*)ws;                    // 67108864 B (NHWC bf16)
    __hip_bfloat16* w2 = (__hip_bfloat16*)(ws + 67108864);       //  4718592 B
    float* s     = (float*)(ws + 71827456);                      //    32768 B
    float* demod = (float*)(ws + 71860224);                      //    32768 B
    float* wsq   = (float*)(ws + 71892992);                      //  1048576 B
    float* zbuf  = (float*)(ws + 72941568);                      //      256 B (zero page)

    static int lds_set = 0;
    if (!lds_set) {
        (void)hipFuncSetAttribute((const void*)conv_kernel,
                                  hipFuncAttributeMaxDynamicSharedMemorySize, 65536);
        lds_set = 1;
    }

    style_kernel<<<2048, 256, 0, stream>>>(w, lin_w, lin_b, s);
    prep_weights<<<512, 256, 0, stream>>>(conv_w, w2, wsq, zbuf);
    demod_kernel<<<2048, 256, 0, stream>>>(wsq, s, demod);
    upsample_mod_kernel<<<dim3(4, 16, 16), 256, 0, stream>>>(x, s, xq);
    conv_kernel<<<512, 512, 65536, stream>>>(xq, w2, demod, noise, nw, out,
                                             (const __hip_bfloat16*)zbuf);
}